// Round 1
// 322.800 us; speedup vs baseline: 1.0249x; 1.0249x over previous
//
#include <hip/hip_runtime.h>
#include <math.h>

#define NUM_BINS 15
#define CCLS 100
#define BLOCK 256
#define GRID 768                 // 3 blocks/CU exactly (LDS-limited), 768%8==0
#define WPB (BLOCK / 64)         // 4 waves per block
#define TROWS 16                 // rows per tile
#define TFLOATS (TROWS * CCLS)   // 1600 floats = 6400 B per tile
#define NXCD 8

// --- global->LDS DMA helpers (size must be a literal constant) ---
__device__ __forceinline__ void dma16(const float* gp, float* lp) {
    __builtin_amdgcn_global_load_lds(
        (const __attribute__((address_space(1))) void*)gp,
        (__attribute__((address_space(3))) void*)lp, 16, 0, 0);
}
__device__ __forceinline__ void dma4(const float* gp, float* lp) {
    __builtin_amdgcn_global_load_lds(
        (const __attribute__((address_space(1))) void*)gp,
        (__attribute__((address_space(3))) void*)lp, 4, 0, 0);
}

// Wave-private double-buffered pipeline:
//   per tile (16 rows = 6400 B): 6x dma16 (1024 B each) + 1x dma4 (256 B)
//   + next tile's label load  => 8 VMEM ops/tile.
// Hot loop: issue tile i+1 -> s_waitcnt vmcnt(8) (counted, never 0) -> consume
// tile i from LDS. No __syncthreads in the loop (waves fully independent).
// LDS tile is LINEAR [16][100]: quarter-row b32 reads hit each bank with
// exactly 2 lanes (4r, +25q cosets disjoint mod 4) = conflict-free per m136.
__global__ __launch_bounds__(BLOCK) void ece_stream(
    const float* __restrict__ logits,
    const int* __restrict__ labels,
    float* __restrict__ ws,   // [0..14]: sum(conf-pred); int ticket at ws[48]
    float* __restrict__ out,
    int n_rows)
{
    __shared__ float s_buf[WPB][2][TFLOATS];   // 51200 B
    __shared__ float s_bin[NUM_BINS];
    __shared__ int s_last;

    const int tid  = threadIdx.x;
    const int lane = tid & 63;
    const int wave = tid >> 6;

    if (tid < NUM_BINS) s_bin[tid] = 0.f;
    __syncthreads();

    // XCD swizzle: XCD x (= b%8) gets a contiguous span of 96 blocks -> each
    // XCD streams a contiguous ~13 MB region of logits.
    const int b  = blockIdx.x;
    const int bp = (b & 7) * (GRID / NXCD) + (b >> 3);
    const int gw = bp * WPB + wave;                 // 0..3071
    const int n_waves = GRID * WPB;

    // contiguous tile distribution: first `trem` waves get tq+1 tiles
    const int ntiles = n_rows / TROWS;              // 32768
    const int tq   = ntiles / n_waves;              // 10
    const int trem = ntiles - tq * n_waves;         // 2048
    const int nt = tq + (gw < trem ? 1 : 0);
    const int t0 = gw * tq + (gw < trem ? gw : trem);

    const int q = lane >> 4;          // quarter-row 0..3 (25 cols each)
    const int r = lane & 15;          // row within tile

    float* cur = s_buf[wave][0];
    float* nxt = s_buf[wave][1];

    // ---- prologue: stage tile t0 + its label (8 VMEM in flight) ----
    int lab_cur;
    {
        const float* g = logits + (size_t)t0 * TFLOATS;
        #pragma unroll
        for (int k = 0; k < 6; ++k)
            dma16(g + k * 256 + lane * 4, cur + k * 256);
        dma4(g + 1536 + lane, cur + 1536);
        lab_cur = labels[t0 * TROWS + r];
    }

    int lab_nxt = 0;
    for (int i = 0; i < nt; ++i) {
        const int t = t0 + i;

        if (i + 1 < nt) {
            // prior iteration's reads of `nxt` are fully consumed; drain LDS
            // queue before the DMA engine overwrites that buffer (cheap).
            asm volatile("s_waitcnt lgkmcnt(0)" ::: "memory");
            const float* g = logits + (size_t)(t + 1) * TFLOATS;
            #pragma unroll
            for (int k = 0; k < 6; ++k)
                dma16(g + k * 256 + lane * 4, nxt + k * 256);
            dma4(g + 1536 + lane, nxt + 1536);
            lab_nxt = labels[(t + 1) * TROWS + r];
            // counted wait: the 8 just-issued stay in flight; tile i's 8
            // (issued last iteration) are guaranteed landed.
            asm volatile("s_waitcnt vmcnt(8)" ::: "memory");
        } else {
            asm volatile("s_waitcnt vmcnt(0)" ::: "memory");
        }
        __builtin_amdgcn_sched_barrier(0);

        // ---- consume: 4 lanes per row, 25 cols each (wave-synchronous) ----
        const float* srow = cur + r * CCLS + q * 25;
        float m = -1e30f, e = 0.f;
        #pragma unroll
        for (int c = 0; c < 25; ++c) {
            const float x = srow[c];
            m = fmaxf(m, x);
            e += __expf(x);
        }
        float tp = 0.f;
        if (lab_cur / 25 == q)                    // owning quarter reads target
            tp = __expf(cur[r * CCLS + lab_cur]);

        #pragma unroll
        for (int off = 16; off <= 32; off <<= 1) {
            m  = fmaxf(m, __shfl_xor(m, off));
            e  += __shfl_xor(e, off);
            tp += __shfl_xor(tp, off);
        }

        if (q == 0) {
            const float inv  = 1.0f / e;
            const float conf = __expf(m) * inv;
            const float diff = conf - tp * inv;
            int bin = (int)(conf * (float)NUM_BINS);
            bin = bin > NUM_BINS - 1 ? NUM_BINS - 1 : bin;
            atomicAdd(&s_bin[bin], diff);
        }

        lab_cur = lab_nxt;
        float* tmp = cur; cur = nxt; nxt = tmp;
    }

    __syncthreads();
    if (tid < NUM_BINS) atomicAdd(&ws[tid], s_bin[tid]);
    __syncthreads();

    // ---- ticket: last block folds ECE = sum_b |ws[b]| / N ----
    if (tid == 0) {
        __threadfence();
        const int tkt = atomicAdd((int*)(ws + 48), 1);
        s_last = (tkt == GRID - 1) ? 1 : 0;
    }
    __syncthreads();
    if (s_last && tid < 64) {
        __threadfence();
        float contrib = 0.f;
        if (tid < NUM_BINS) {
            const float v = __hip_atomic_load(&ws[tid], __ATOMIC_RELAXED,
                                              __HIP_MEMORY_SCOPE_AGENT);
            contrib = fabsf(v);
        }
        #pragma unroll
        for (int off = 32; off >= 1; off >>= 1)
            contrib += __shfl_xor(contrib, off);
        if (tid == 0) out[0] = contrib / (float)n_rows;
    }
}

extern "C" void kernel_launch(void* const* d_in, const int* in_sizes, int n_in,
                              void* d_out, int out_size, void* d_ws, size_t ws_size,
                              hipStream_t stream)
{
    const float* logits = (const float*)d_in[0];
    const int*   labels = (const int*)d_in[1];
    float* out = (float*)d_out;
    float* ws  = (float*)d_ws;

    const int n_rows = in_sizes[1];   // 524288

    // ws re-poisoned to 0xAA before every timed launch — zero accumulators+ticket.
    hipMemsetAsync(ws, 0, 64 * sizeof(float), stream);

    ece_stream<<<dim3(GRID), dim3(BLOCK), 0, stream>>>(logits, labels, ws, out, n_rows);
}